// Round 2
// baseline (740.322 us; speedup 1.0000x reference)
//
#include <hip/hip_runtime.h>

#define TOKENS 4096
#define IN_F   8192
#define OUT_F  8192
#define BK     64
#define TILEB  32768          /* per-buffer LDS: A 256*64 + B 256*64 */
#define NT     (IN_F / BK)    /* 128 K-tiles */

typedef int v4i  __attribute__((ext_vector_type(4)));
typedef int v16i __attribute__((ext_vector_type(16)));

__device__ __forceinline__ void gload_lds16(const void* g, void* l) {
    __builtin_amdgcn_global_load_lds(
        (const __attribute__((address_space(1))) void*)g,
        (__attribute__((address_space(3))) void*)l, 16, 0, 0);
}

// ---------------- Kernel 1: per-row absmax + int8 quantize ----------------
__global__ __launch_bounds__(256) void quant_kernel(const float* __restrict__ x,
                                                    signed char* __restrict__ xq,
                                                    float* __restrict__ recip_s) {
    const int row = blockIdx.x;
    const int t   = threadIdx.x;
    const float4* xr = (const float4*)(x + (size_t)row * IN_F);
    float4 v[8];
    float m = 0.f;
#pragma unroll
    for (int i = 0; i < 8; ++i) {
        v[i] = xr[t + 256 * i];
        m = fmaxf(m, fmaxf(fmaxf(fabsf(v[i].x), fabsf(v[i].y)),
                           fmaxf(fabsf(v[i].z), fabsf(v[i].w))));
    }
#pragma unroll
    for (int off = 32; off > 0; off >>= 1)
        m = fmaxf(m, __shfl_xor(m, off));
    __shared__ float wmax[4];
    if ((t & 63) == 0) wmax[t >> 6] = m;
    __syncthreads();
    m = fmaxf(fmaxf(wmax[0], wmax[1]), fmaxf(wmax[2], wmax[3]));
    m = fmaxf(m, 1e-5f);
    const float s = 127.0f / m;          // matches ref: s = 127/clip(max,1e-5)
    if (t == 0) recip_s[row] = m / 127.0f;
    unsigned int* out = (unsigned int*)(xq + (size_t)row * IN_F);
#pragma unroll
    for (int i = 0; i < 8; ++i) {
        int a = (int)fminf(fmaxf(rintf(v[i].x * s), -128.f), 127.f);
        int b = (int)fminf(fmaxf(rintf(v[i].y * s), -128.f), 127.f);
        int c = (int)fminf(fmaxf(rintf(v[i].z * s), -128.f), 127.f);
        int d = (int)fminf(fmaxf(rintf(v[i].w * s), -128.f), 127.f);
        out[t + 256 * i] = (a & 255) | ((b & 255) << 8) | ((c & 255) << 16) | ((d & 255) << 24);
    }
}

// ---------------- Kernel 2: weight int32 {0,1} -> int8 ----------------
__global__ __launch_bounds__(256) void pack_w(const int* __restrict__ w,
                                              unsigned int* __restrict__ w8) {
    const size_t idx = (size_t)blockIdx.x * 256 + threadIdx.x;
    int4 a = ((const int4*)w)[idx];
    w8[idx] = (a.x & 255) | ((a.y & 255) << 8) | ((a.z & 255) << 16) | ((a.w & 255) << 24);
}

// ---------------- Kernel 3: i8 GEMM, 256x256 block, 128x128 wave tile ----
// 4 waves (2x2), mfma_i32_32x32x32_i8, 1 wave/SIMD (256 acc regs).
// Triple-buffered LDS (96 KB) + counted vmcnt(8) + register-fragment
// double-buffer: ds_reads for tile k+1 issue before the MFMA cluster of
// tile k, so LDS latency hides under the ~1170-cy MFMA cluster.
// LDS chunk swizzle: 16B chunk c of row r stored at c ^ ((r>>1)&3)
// (applied at the pre-swizzled global source; dest stays linear).
__global__ __launch_bounds__(256, 1) void gemm_kernel(const signed char* __restrict__ A,
                                                      const signed char* __restrict__ B,
                                                      const float* __restrict__ recip_s,
                                                      const float* __restrict__ wscale,
                                                      const float* __restrict__ bias,
                                                      float* __restrict__ out) {
    __shared__ signed char smem[3 * TILEB];   // 96 KB -> 1 block/CU
    const int t    = threadIdx.x;
    const int wave = t >> 6;
    const int lane = t & 63;

    // Bijective XCD swizzle (512 blocks, 512%8==0) + m-fastest decode so
    // consecutive co-resident blocks on one XCD share a 2MB B panel in L2.
    const int bid = blockIdx.x;
    const int swz = (bid & 7) * 64 + (bid >> 3);
    const int m0  = (swz & 15) * 256;
    const int n0  = (swz >> 4) * 256;

    const int wm = (wave >> 1) * 128;   // wave row offset (M)
    const int wn = (wave & 1) * 128;    // wave col offset (N)

    v16i acc[4][4] = {};

    // staging: 256 threads x 16B = 4KB per gload (64 rows of 64B); 8 calls
    // cover A(256x64) + B(256x64). Source chunk pre-swizzled.
    const int rowS = t >> 2;                           // 0..63
    const int colS = ((t & 3) ^ ((t >> 3) & 3)) * 16;  // swizzled source chunk
    const signed char* gA = A + (size_t)(m0 + rowS) * IN_F + colS;
    const signed char* gB = B + (size_t)(n0 + rowS) * IN_F + colS;

    // fragment read addressing: a(i,kk) at row = wm + i*32 + (lane&31),
    // byte = row*64 + ((kk*2 + (lane>>5)) ^ ((row>>1)&3))*16.
    // (wm, i*32 contribute 0 mod 4 to (row>>1)&3 -> s depends on lane only)
    const int l31 = lane & 31;
    const int q5  = lane >> 5;
    const int s   = (l31 >> 1) & 3;
    const int aO0 = (wm + l31) * 64 + (((0 + q5) ^ s) * 16);
    const int aO1 = (wm + l31) * 64 + (((2 + q5) ^ s) * 16);
    const int bO0 = 16384 + (wn + l31) * 64 + (((0 + q5) ^ s) * 16);
    const int bO1 = 16384 + (wn + l31) * 64 + (((2 + q5) ^ s) * 16);

    v4i aF0[8], bF0[8], aF1[8], bF1[8];

#define STAGE(kt, b3) do {                                                   \
        signed char* l0 = smem + (b3) * TILEB + t * 16;                      \
        const size_t ko = (size_t)(kt) * BK;                                 \
        gload_lds16(gA + ko,                        l0);                     \
        gload_lds16(gA + (size_t)64  * IN_F + ko,   l0 + 4096);              \
        gload_lds16(gA + (size_t)128 * IN_F + ko,   l0 + 8192);              \
        gload_lds16(gA + (size_t)192 * IN_F + ko,   l0 + 12288);             \
        gload_lds16(gB + ko,                        l0 + 16384);             \
        gload_lds16(gB + (size_t)64  * IN_F + ko,   l0 + 20480);             \
        gload_lds16(gB + (size_t)128 * IN_F + ko,   l0 + 24576);             \
        gload_lds16(gB + (size_t)192 * IN_F + ko,   l0 + 28672);             \
    } while (0)

#define FRAGS(b3, aF, bF) do {                                               \
        const signed char* bp = smem + (b3) * TILEB;                         \
        _Pragma("unroll")                                                    \
        for (int i = 0; i < 4; ++i) {                                        \
            aF[i * 2 + 0] = *(const v4i*)(bp + aO0 + i * 2048);              \
            aF[i * 2 + 1] = *(const v4i*)(bp + aO1 + i * 2048);              \
            bF[i * 2 + 0] = *(const v4i*)(bp + bO0 + i * 2048);              \
            bF[i * 2 + 1] = *(const v4i*)(bp + bO1 + i * 2048);              \
        }                                                                    \
    } while (0)

#define MM(aF, bF) do {                                                      \
        __builtin_amdgcn_s_setprio(1);                                       \
        _Pragma("unroll")                                                    \
        for (int kk = 0; kk < 2; ++kk)                                       \
            _Pragma("unroll")                                                \
            for (int i = 0; i < 4; ++i)                                      \
                _Pragma("unroll")                                            \
                for (int j = 0; j < 4; ++j)                                  \
                    acc[i][j] = __builtin_amdgcn_mfma_i32_32x32x32_i8(       \
                        aF[i * 2 + kk], bF[j * 2 + kk], acc[i][j], 0, 0, 0); \
        __builtin_amdgcn_s_setprio(0);                                       \
    } while (0)

    // Per K-step: stage k+2, counted-wait (tile k+1 landed), barrier,
    // issue frag reads for k+1, MFMA tile k (compiler emits counted lgkmcnt).
#define BODY(kt, b3s, b3f, aN, bN, aC, bC) do {                              \
        STAGE((kt) + 2, b3s);                                                \
        asm volatile("s_waitcnt vmcnt(8)" ::: "memory");                     \
        __builtin_amdgcn_s_barrier();                                        \
        asm volatile("" ::: "memory");                                       \
        FRAGS(b3f, aN, bN);                                                  \
        MM(aC, bC);                                                          \
    } while (0)

    // Prologue: tiles 0,1 staged; tile0 landed; tile0 frags issued.
    STAGE(0, 0);
    STAGE(1, 1);
    asm volatile("s_waitcnt vmcnt(8)" ::: "memory");
    __builtin_amdgcn_s_barrier();
    asm volatile("" ::: "memory");
    FRAGS(0, aF0, bF0);

    // Main loop: k = 0..125, unrolled x6 (LCM of 3 LDS bufs, 2 frag sets).
    for (int kt = 0; kt < NT - 2; kt += 6) {
        BODY(kt + 0, 2, 1, aF1, bF1, aF0, bF0);
        BODY(kt + 1, 0, 2, aF0, bF0, aF1, bF1);
        BODY(kt + 2, 1, 0, aF1, bF1, aF0, bF0);
        BODY(kt + 3, 2, 1, aF0, bF0, aF1, bF1);
        BODY(kt + 4, 0, 2, aF1, bF1, aF0, bF0);
        BODY(kt + 5, 1, 0, aF0, bF0, aF1, bF1);
    }
    // Tail: tiles 126 (frags in set0, staged buf0) and 127 (buf1).
    asm volatile("s_waitcnt vmcnt(0)" ::: "memory");
    __builtin_amdgcn_s_barrier();
    asm volatile("" ::: "memory");
    FRAGS(1, aF1, bF1);
    MM(aF0, bF0);
    MM(aF1, bF1);

#undef STAGE
#undef FRAGS
#undef MM
#undef BODY

    // Epilogue: dequant + bias. C/D 32x32 map: col=lane&31,
    // row=(r&3)+8*(r>>2)+4*(lane>>5).
    const float rws = 1.0f / wscale[0];
    float bj[4];
#pragma unroll
    for (int j = 0; j < 4; ++j) bj[j] = bias[n0 + wn + j * 32 + l31];
#pragma unroll
    for (int i = 0; i < 4; ++i) {
#pragma unroll
        for (int r = 0; r < 16; ++r) {
            const int row = m0 + wm + i * 32 + (r & 3) + 8 * (r >> 2) + 4 * q5;
            const float rs = recip_s[row] * rws;
#pragma unroll
            for (int j = 0; j < 4; ++j) {
                const int col = n0 + wn + j * 32 + l31;
                out[(size_t)row * OUT_F + col] = (float)acc[i][j][r] * rs + bj[j];
            }
        }
    }
}

extern "C" void kernel_launch(void* const* d_in, const int* in_sizes, int n_in,
                              void* d_out, int out_size, void* d_ws, size_t ws_size,
                              hipStream_t stream) {
    const float* x      = (const float*)d_in[0];
    const int*   w      = (const int*)d_in[1];
    const float* wscale = (const float*)d_in[2];
    const float* bias   = (const float*)d_in[3];
    float* out = (float*)d_out;

    signed char* xq = (signed char*)d_ws;                          // 32 MB
    signed char* w8 = xq + (size_t)TOKENS * IN_F;                  // 64 MB
    float* recip_s  = (float*)(w8 + (size_t)OUT_F * IN_F);         // 16 KB

    quant_kernel<<<TOKENS, 256, 0, stream>>>(x, xq, recip_s);
    pack_w<<<(int)(((size_t)OUT_F * IN_F) / 4 / 256), 256, 0, stream>>>(w, (unsigned int*)w8);
    gemm_kernel<<<(TOKENS / 256) * (OUT_F / 256), 256, 0, stream>>>(xq, w8, recip_s, wscale, bias, out);
}

// Round 5
// 734.849 us; speedup vs baseline: 1.0074x; 1.0074x over previous
//
#include <hip/hip_runtime.h>

#define TOKENS 4096
#define IN_F   8192
#define OUT_F  8192
#define BK     64
#define TILEB  32768          /* per-buffer LDS: A 256*64 + B 256*64 */
#define NT     (IN_F / BK)    /* 128 K-tiles */

typedef int v4i __attribute__((ext_vector_type(4)));

__device__ __forceinline__ void gload_lds16(const void* g, void* l) {
    __builtin_amdgcn_global_load_lds(
        (const __attribute__((address_space(1))) void*)g,
        (__attribute__((address_space(3))) void*)l, 16, 0, 0);
}

// ---------------- Kernel 1: per-row absmax + int8 quantize ----------------
__global__ __launch_bounds__(256) void quant_kernel(const float* __restrict__ x,
                                                    signed char* __restrict__ xq,
                                                    float* __restrict__ recip_s) {
    const int row = blockIdx.x;
    const int t   = threadIdx.x;
    const float4* xr = (const float4*)(x + (size_t)row * IN_F);
    float4 v[8];
    float m = 0.f;
#pragma unroll
    for (int i = 0; i < 8; ++i) {
        v[i] = xr[t + 256 * i];
        m = fmaxf(m, fmaxf(fmaxf(fabsf(v[i].x), fabsf(v[i].y)),
                           fmaxf(fabsf(v[i].z), fabsf(v[i].w))));
    }
#pragma unroll
    for (int off = 32; off > 0; off >>= 1)
        m = fmaxf(m, __shfl_xor(m, off));
    __shared__ float wmax[4];
    if ((t & 63) == 0) wmax[t >> 6] = m;
    __syncthreads();
    m = fmaxf(fmaxf(wmax[0], wmax[1]), fmaxf(wmax[2], wmax[3]));
    m = fmaxf(m, 1e-5f);
    const float s = 127.0f / m;          // matches ref: s = 127/clip(max,1e-5)
    if (t == 0) recip_s[row] = m / 127.0f;
    unsigned int* out = (unsigned int*)(xq + (size_t)row * IN_F);
#pragma unroll
    for (int i = 0; i < 8; ++i) {
        int a = (int)fminf(fmaxf(rintf(v[i].x * s), -128.f), 127.f);
        int b = (int)fminf(fmaxf(rintf(v[i].y * s), -128.f), 127.f);
        int c = (int)fminf(fmaxf(rintf(v[i].z * s), -128.f), 127.f);
        int d = (int)fminf(fmaxf(rintf(v[i].w * s), -128.f), 127.f);
        out[t + 256 * i] = (a & 255) | ((b & 255) << 8) | ((c & 255) << 16) | ((d & 255) << 24);
    }
}

// ---------------- Kernel 2: weight int32 {0,1} -> int8 ----------------
__global__ __launch_bounds__(256) void pack_w(const int* __restrict__ w,
                                              unsigned int* __restrict__ w8) {
    const size_t idx = (size_t)blockIdx.x * 256 + threadIdx.x;
    int4 a = ((const int4*)w)[idx];
    w8[idx] = (a.x & 255) | ((a.y & 255) << 8) | ((a.z & 255) << 16) | ((a.w & 255) << 24);
}

// ---------------- Kernel 3: i8 GEMM, 256x256 block, 128x128 wave tile ----
// 4 waves (2x2), mfma_i32_16x16x64_i8 (R1's hardware-verified ZERO-conflict
// LDS read walk: 16-row span, 4-way chunk spread), 1 wave/SIMD.
// Triple-buffered LDS (96 KB) + counted vmcnt(8) + register-fragment
// double-buffer (frag reads for tile k+1 issue before MFMA cluster of k).
// LDS chunk swizzle: 16B chunk c of row r stored at c ^ ((r>>1)&3)
// (applied at the pre-swizzled global source; dest stays linear).
__global__ __launch_bounds__(256, 1) void gemm_kernel(const signed char* __restrict__ A,
                                                      const signed char* __restrict__ B,
                                                      const float* __restrict__ recip_s,
                                                      const float* __restrict__ wscale,
                                                      const float* __restrict__ bias,
                                                      float* __restrict__ out) {
    __shared__ signed char smem[3 * TILEB];   // 96 KB -> 1 block/CU
    const int t    = threadIdx.x;
    const int wave = t >> 6;
    const int lane = t & 63;

    // Bijective XCD swizzle (512 blocks, 512%8==0) + m-fastest decode so
    // consecutive co-resident blocks on one XCD share a 2MB B panel in L2.
    const int bid = blockIdx.x;
    const int swz = (bid & 7) * 64 + (bid >> 3);
    const int m0  = (swz & 15) * 256;
    const int n0  = (swz >> 4) * 256;

    const int wm = (wave >> 1) * 128;   // wave row offset (M)
    const int wn = (wave & 1) * 128;    // wave col offset (N)

    v4i acc[8][8] = {};

    // staging: 256 threads x 16B = 4KB per gload (64 rows of 64B); 8 calls
    // cover A(256x64) + B(256x64). Source chunk pre-swizzled.
    const int rowS = t >> 2;                           // 0..63
    const int colS = ((t & 3) ^ ((t >> 3) & 3)) * 16;  // swizzled source chunk
    const signed char* gA = A + (size_t)(m0 + rowS) * IN_F + colS;
    const signed char* gB = B + (size_t)(n0 + rowS) * IN_F + colS;

    // fragment reads (R1's zero-conflict walk): frag row = wm + i*16 + r16,
    // chunk position = q ^ ((r16>>1)&3)  (wm, i*16 are 0 mod 8 -> row swizzle
    // term depends only on r16).
    const int r16 = lane & 15;
    const int q   = lane >> 4;
    const int cOff = (q ^ ((r16 >> 1) & 3)) * 16;
    const int aBase = (wm + r16) * 64 + cOff;
    const int bBase = 16384 + (wn + r16) * 64 + cOff;

    v4i aF0[8], bF0[8], aF1[8], bF1[8];

#define STAGE(kt, b3) do {                                                   \
        signed char* l0 = smem + (b3) * TILEB + t * 16;                      \
        const size_t ko = (size_t)(kt) * BK;                                 \
        gload_lds16(gA + ko,                        l0);                     \
        gload_lds16(gA + (size_t)64  * IN_F + ko,   l0 + 4096);              \
        gload_lds16(gA + (size_t)128 * IN_F + ko,   l0 + 8192);              \
        gload_lds16(gA + (size_t)192 * IN_F + ko,   l0 + 12288);             \
        gload_lds16(gB + ko,                        l0 + 16384);             \
        gload_lds16(gB + (size_t)64  * IN_F + ko,   l0 + 20480);             \
        gload_lds16(gB + (size_t)128 * IN_F + ko,   l0 + 24576);             \
        gload_lds16(gB + (size_t)192 * IN_F + ko,   l0 + 28672);             \
    } while (0)

#define FRAGS(b3, aF, bF) do {                                               \
        const signed char* bp = smem + (b3) * TILEB;                         \
        _Pragma("unroll")                                                    \
        for (int i = 0; i < 8; ++i) {                                        \
            aF[i] = *(const v4i*)(bp + aBase + i * 1024);                    \
            bF[i] = *(const v4i*)(bp + bBase + i * 1024);                    \
        }                                                                    \
    } while (0)

#define MM(aF, bF) do {                                                      \
        __builtin_amdgcn_s_setprio(1);                                       \
        _Pragma("unroll")                                                    \
        for (int i = 0; i < 8; ++i)                                          \
            _Pragma("unroll")                                                \
            for (int j = 0; j < 8; ++j)                                      \
                acc[i][j] = __builtin_amdgcn_mfma_i32_16x16x64_i8(           \
                    aF[i], bF[j], acc[i][j], 0, 0, 0);                       \
        __builtin_amdgcn_s_setprio(0);                                       \
    } while (0)

    // Per K-step: stage k+2, counted-wait (tile k+1 landed), barrier,
    // issue frag reads for k+1, MFMA tile k (compiler emits counted lgkmcnt).
#define BODY(kt, b3s, b3f, aN, bN, aC, bC) do {                              \
        STAGE((kt) + 2, b3s);                                                \
        asm volatile("s_waitcnt vmcnt(8)" ::: "memory");                     \
        __builtin_amdgcn_s_barrier();                                        \
        asm volatile("" ::: "memory");                                       \
        FRAGS(b3f, aN, bN);                                                  \
        MM(aC, bC);                                                          \
    } while (0)

    // Prologue: tiles 0,1 staged; tile0 landed; tile0 frags issued.
    STAGE(0, 0);
    STAGE(1, 1);
    asm volatile("s_waitcnt vmcnt(8)" ::: "memory");
    __builtin_amdgcn_s_barrier();
    asm volatile("" ::: "memory");
    FRAGS(0, aF0, bF0);

    // Main loop: k = 0..125, unrolled x6 (LCM of 3 LDS bufs, 2 frag sets).
    for (int kt = 0; kt < NT - 2; kt += 6) {
        BODY(kt + 0, 2, 1, aF1, bF1, aF0, bF0);
        BODY(kt + 1, 0, 2, aF0, bF0, aF1, bF1);
        BODY(kt + 2, 1, 0, aF1, bF1, aF0, bF0);
        BODY(kt + 3, 2, 1, aF0, bF0, aF1, bF1);
        BODY(kt + 4, 0, 2, aF1, bF1, aF0, bF0);
        BODY(kt + 5, 1, 0, aF0, bF0, aF1, bF1);
    }
    // Tail: tile 126 (frags already in set0, buf0 staged) and 127 (buf1).
    asm volatile("s_waitcnt vmcnt(0)" ::: "memory");
    __builtin_amdgcn_s_barrier();
    asm volatile("" ::: "memory");
    FRAGS(1, aF1, bF1);
    MM(aF0, bF0);
    MM(aF1, bF1);

#undef STAGE
#undef FRAGS
#undef MM
#undef BODY

    // Epilogue: dequant + bias. 16x16 C/D map: col = lane&15,
    // row = (lane>>4)*4 + r  (R0/R1-verified).
    const float rws = 1.0f / wscale[0];
    float bj[8];
#pragma unroll
    for (int j = 0; j < 8; ++j) bj[j] = bias[n0 + wn + j * 16 + r16];
#pragma unroll
    for (int i = 0; i < 8; ++i) {
#pragma unroll
        for (int r = 0; r < 4; ++r) {
            const int row = m0 + wm + i * 16 + q * 4 + r;
            const float rs = recip_s[row] * rws;
#pragma unroll
            for (int j = 0; j < 8; ++j) {
                const int col = n0 + wn + j * 16 + r16;
                out[(size_t)row * OUT_F + col] = (float)acc[i][j][r] * rs + bj[j];
            }
        }
    }
}

extern "C" void kernel_launch(void* const* d_in, const int* in_sizes, int n_in,
                              void* d_out, int out_size, void* d_ws, size_t ws_size,
                              hipStream_t stream) {
    const float* x      = (const float*)d_in[0];
    const int*   w      = (const int*)d_in[1];
    const float* wscale = (const float*)d_in[2];
    const float* bias   = (const float*)d_in[3];
    float* out = (float*)d_out;

    signed char* xq = (signed char*)d_ws;                          // 32 MB
    signed char* w8 = xq + (size_t)TOKENS * IN_F;                  // 64 MB
    float* recip_s  = (float*)(w8 + (size_t)OUT_F * IN_F);         // 16 KB

    quant_kernel<<<TOKENS, 256, 0, stream>>>(x, xq, recip_s);
    pack_w<<<(int)(((size_t)OUT_F * IN_F) / 4 / 256), 256, 0, stream>>>(w, (unsigned int*)w8);
    gemm_kernel<<<(TOKENS / 256) * (OUT_F / 256), 256, 0, stream>>>(xq, w8, recip_s, wscale, bias, out);
}

// Round 7
// 713.248 us; speedup vs baseline: 1.0380x; 1.0303x over previous
//
#include <hip/hip_runtime.h>

#define TOKENS 4096
#define IN_F   8192
#define OUT_F  8192
#define BK     64
#define TILEB  32768          /* per-buffer LDS: A 256*64 + B 256*64 */
#define NT     (IN_F / BK)    /* 128 K-tiles */

typedef int v4i __attribute__((ext_vector_type(4)));

__device__ __forceinline__ void gload_lds16(const void* g, void* l) {
    __builtin_amdgcn_global_load_lds(
        (const __attribute__((address_space(1))) void*)g,
        (__attribute__((address_space(3))) void*)l, 16, 0, 0);
}

// ---------------- Kernel 1: per-row absmax + int8 quantize ----------------
__global__ __launch_bounds__(256) void quant_kernel(const float* __restrict__ x,
                                                    signed char* __restrict__ xq,
                                                    float* __restrict__ recip_s) {
    const int row = blockIdx.x;
    const int t   = threadIdx.x;
    const float4* xr = (const float4*)(x + (size_t)row * IN_F);
    float4 v[8];
    float m = 0.f;
#pragma unroll
    for (int i = 0; i < 8; ++i) {
        v[i] = xr[t + 256 * i];
        m = fmaxf(m, fmaxf(fmaxf(fabsf(v[i].x), fabsf(v[i].y)),
                           fmaxf(fabsf(v[i].z), fabsf(v[i].w))));
    }
#pragma unroll
    for (int off = 32; off > 0; off >>= 1)
        m = fmaxf(m, __shfl_xor(m, off));
    __shared__ float wmax[4];
    if ((t & 63) == 0) wmax[t >> 6] = m;
    __syncthreads();
    m = fmaxf(fmaxf(wmax[0], wmax[1]), fmaxf(wmax[2], wmax[3]));
    m = fmaxf(m, 1e-5f);
    const float s = 127.0f / m;          // matches ref: s = 127/clip(max,1e-5)
    if (t == 0) recip_s[row] = m / 127.0f;
    unsigned int* out = (unsigned int*)(xq + (size_t)row * IN_F);
#pragma unroll
    for (int i = 0; i < 8; ++i) {
        int a = (int)fminf(fmaxf(rintf(v[i].x * s), -128.f), 127.f);
        int b = (int)fminf(fmaxf(rintf(v[i].y * s), -128.f), 127.f);
        int c = (int)fminf(fmaxf(rintf(v[i].z * s), -128.f), 127.f);
        int d = (int)fminf(fmaxf(rintf(v[i].w * s), -128.f), 127.f);
        out[t + 256 * i] = (a & 255) | ((b & 255) << 8) | ((c & 255) << 16) | ((d & 255) << 24);
    }
}

// ---------------- Kernel 2: weight int32 {0,1} -> int8 ----------------
__global__ __launch_bounds__(256) void pack_w(const int* __restrict__ w,
                                              unsigned int* __restrict__ w8) {
    const size_t idx = (size_t)blockIdx.x * 256 + threadIdx.x;
    int4 a = ((const int4*)w)[idx];
    w8[idx] = (a.x & 255) | ((a.y & 255) << 8) | ((a.z & 255) << 16) | ((a.w & 255) << 24);
}

// ---------------- Kernel 3: i8 GEMM, 256x256 block, 8 waves, 128x64/wave --
// m201 geometry: 512 threads, 8 waves (2M x 4N), wave tile 128x64 ->
// acc 128 regs + dbuf frags 96 -> ~240 VGPR -> 2 waves/SIMD (the TLP that
// R5's 1-wave/SIMD lacked). mfma_i32_16x16x64_i8 with the measured
// zero-conflict LDS walk. Triple-buffered LDS (96 KB), counted vmcnt(4),
// cross-step register-fragment double-buffer, one barrier per K-step.
// LDS chunk swizzle: 16B chunk c of row r stored at c ^ ((r>>1)&3)
// (applied at the pre-swizzled global source; dest stays linear).
__global__ __launch_bounds__(512, 2) void gemm_kernel(const signed char* __restrict__ A,
                                                      const signed char* __restrict__ B,
                                                      const float* __restrict__ recip_s,
                                                      const float* __restrict__ wscale,
                                                      const float* __restrict__ bias,
                                                      float* __restrict__ out) {
    __shared__ signed char smem[3 * TILEB];   // 96 KB -> 1 block/CU
    const int t    = threadIdx.x;
    const int wave = t >> 6;
    const int lane = t & 63;

    // Bijective XCD swizzle (512 blocks, 512%8==0) + m-fastest decode.
    const int bid = blockIdx.x;
    const int swz = (bid & 7) * 64 + (bid >> 3);
    const int m0  = (swz & 15) * 256;
    const int n0  = (swz >> 4) * 256;

    const int wm = (wave >> 2) * 128;   // wave row offset (M): 2 rows of waves
    const int wn = (wave & 3) * 64;     // wave col offset (N): 4 cols of waves

    v4i acc[8][4] = {};                 // 128x64 wave tile

    // staging: 512 threads x 16B = 8KB per gload call (128 rows of 64B);
    // 4 calls cover A(256x64) + B(256x64). Source chunk pre-swizzled.
    const int rowS = t >> 2;                           // 0..127
    const int colS = ((t & 3) ^ ((t >> 3) & 3)) * 16;  // swizzled source chunk
    const signed char* gA = A + (size_t)(m0 + rowS) * IN_F + colS;
    const signed char* gB = B + (size_t)(n0 + rowS) * IN_F + colS;

    // fragment reads (measured zero-conflict walk): row = base + i*16 + r16,
    // chunk position = q ^ ((r16>>1)&3). wm mult of 128, wn mult of 64 ->
    // swizzle term depends only on r16.
    const int r16 = lane & 15;
    const int q   = lane >> 4;
    const int cOff = (q ^ ((r16 >> 1) & 3)) * 16;
    const int aBase = (wm + r16) * 64 + cOff;
    const int bBase = 16384 + (wn + r16) * 64 + cOff;

    v4i aF0[8], bF0[4], aF1[8], bF1[4];

#define STAGE(kt, b3) do {                                                   \
        signed char* l0 = smem + (b3) * TILEB + t * 16;                      \
        const size_t ko = (size_t)(kt) * BK;                                 \
        gload_lds16(gA + ko,                        l0);                     \
        gload_lds16(gA + (size_t)128 * IN_F + ko,   l0 + 8192);              \
        gload_lds16(gB + ko,                        l0 + 16384);             \
        gload_lds16(gB + (size_t)128 * IN_F + ko,   l0 + 24576);             \
    } while (0)

#define FRAGS(b3, aF, bF) do {                                               \
        const signed char* bp = smem + (b3) * TILEB;                         \
        _Pragma("unroll")                                                    \
        for (int i = 0; i < 8; ++i)                                          \
            aF[i] = *(const v4i*)(bp + aBase + i * 1024);                    \
        _Pragma("unroll")                                                    \
        for (int j = 0; j < 4; ++j)                                          \
            bF[j] = *(const v4i*)(bp + bBase + j * 1024);                    \
    } while (0)

#define MM(aF, bF) do {                                                      \
        __builtin_amdgcn_s_setprio(1);                                       \
        _Pragma("unroll")                                                    \
        for (int i = 0; i < 8; ++i)                                          \
            _Pragma("unroll")                                                \
            for (int j = 0; j < 4; ++j)                                      \
                acc[i][j] = __builtin_amdgcn_mfma_i32_16x16x64_i8(           \
                    aF[i], bF[j], acc[i][j], 0, 0, 0);                       \
        __builtin_amdgcn_s_setprio(0);                                       \
    } while (0)

    // Per K-step t: stage t+2, vmcnt(4) (tile t+1 landed; t+2's 4 in
    // flight), barrier, frag-read tile t+1, MFMA tile t (counted lgkmcnt
    // by compiler). Buffer-overwrite safety: buf (t+2)%3 was last read in
    // region t-2 and fully drained (lgkm) before barrier t-1.
#define BODY(kt, b3s, b3f, aN, bN, aC, bC) do {                              \
        STAGE((kt) + 2, b3s);                                                \
        asm volatile("s_waitcnt vmcnt(4)" ::: "memory");                     \
        __builtin_amdgcn_s_barrier();                                        \
        asm volatile("" ::: "memory");                                       \
        FRAGS(b3f, aN, bN);                                                  \
        MM(aC, bC);                                                          \
    } while (0)

    // Prologue: tiles 0,1 staged; tile0 landed; tile0 frags issued.
    STAGE(0, 0);
    STAGE(1, 1);
    asm volatile("s_waitcnt vmcnt(4)" ::: "memory");
    __builtin_amdgcn_s_barrier();
    asm volatile("" ::: "memory");
    FRAGS(0, aF0, bF0);

    // Main loop: t = 0..125, unrolled x6 (LCM of 3 LDS bufs, 2 frag sets).
    for (int kt = 0; kt < NT - 2; kt += 6) {
        BODY(kt + 0, 2, 1, aF1, bF1, aF0, bF0);
        BODY(kt + 1, 0, 2, aF0, bF0, aF1, bF1);
        BODY(kt + 2, 1, 0, aF1, bF1, aF0, bF0);
        BODY(kt + 3, 2, 1, aF0, bF0, aF1, bF1);
        BODY(kt + 4, 0, 2, aF1, bF1, aF0, bF0);
        BODY(kt + 5, 1, 0, aF0, bF0, aF1, bF1);
    }
    // Tail: tile 126 (frags in set0, buf0) and 127 (buf1).
    asm volatile("s_waitcnt vmcnt(0)" ::: "memory");
    __builtin_amdgcn_s_barrier();
    asm volatile("" ::: "memory");
    FRAGS(1, aF1, bF1);
    MM(aF0, bF0);
    MM(aF1, bF1);

#undef STAGE
#undef FRAGS
#undef MM
#undef BODY

    // Epilogue: dequant + bias. 16x16 C/D map: col = lane&15,
    // row = (lane>>4)*4 + r  (R0/R1-verified).
    const float rws = 1.0f / wscale[0];
    float bj[4];
#pragma unroll
    for (int j = 0; j < 4; ++j) bj[j] = bias[n0 + wn + j * 16 + r16];
#pragma unroll
    for (int i = 0; i < 8; ++i) {
#pragma unroll
        for (int r = 0; r < 4; ++r) {
            const int row = m0 + wm + i * 16 + q * 4 + r;
            const float rs = recip_s[row] * rws;
#pragma unroll
            for (int j = 0; j < 4; ++j) {
                const int col = n0 + wn + j * 16 + r16;
                out[(size_t)row * OUT_F + col] = (float)acc[i][j][r] * rs + bj[j];
            }
        }
    }
}

extern "C" void kernel_launch(void* const* d_in, const int* in_sizes, int n_in,
                              void* d_out, int out_size, void* d_ws, size_t ws_size,
                              hipStream_t stream) {
    const float* x      = (const float*)d_in[0];
    const int*   w      = (const int*)d_in[1];
    const float* wscale = (const float*)d_in[2];
    const float* bias   = (const float*)d_in[3];
    float* out = (float*)d_out;

    signed char* xq = (signed char*)d_ws;                          // 32 MB
    signed char* w8 = xq + (size_t)TOKENS * IN_F;                  // 64 MB
    float* recip_s  = (float*)(w8 + (size_t)OUT_F * IN_F);         // 16 KB

    quant_kernel<<<TOKENS, 256, 0, stream>>>(x, xq, recip_s);
    pack_w<<<(int)(((size_t)OUT_F * IN_F) / 4 / 256), 256, 0, stream>>>(w, (unsigned int*)w8);
    gemm_kernel<<<(TOKENS / 256) * (OUT_F / 256), 512, 0, stream>>>(xq, w8, recip_s, wscale, bias, out);
}